// Round 8
// baseline (41.558 us; speedup 1.0000x reference)
//
#include <hip/hip_runtime.h>

// ResizeFlow: factor-2 trilinear upsample, periodic (dft) wrap, edge anchor,
// then displacement rescale ×2 (folded into z-blend weights: 0.5/1.5).
// Input (2,3,96,96,96) f32 -> Output (2,3,192,192,192) f32.
//
// out[2k]   = 0.25*in[(k-1) mod 96] + 0.75*in[k]
// out[2k+1] = 0.75*in[k]            + 0.25*in[(k+1) mod 96]   (each axis)
//
// R8 mechanism probe: LONG SEQUENTIAL WRITE STREAMS per wave.
// One wave = (bc, input plane k, y-chunk of 8 y-bricks). It loops ty over
// the chunk, producing output planes {2k, 2k+1} rows 4ty..4ty+3 each step:
// per wave, TWO sequential 24 KB write streams (vs R5's 4 scattered 3-4 KB
// chunks per wave, planes 147 KB apart). Chip-wide ~6.9K long streams vs
// ~16K fragments -> better DRAM row-buffer locality for the dominant
// 166 MB write. Lanes 48..63 idle (store BW unaffected; we're DRAM-bound,
// not issue-bound). 3456 one-wave blocks (div 8); chunked XCD swizzle gives
// each XCD a 2.6 MB input slab (fits 4 MB L2) and a contiguous ~21 MB
// output region. Plain float4 stores (nt hurt, R4->R5).

#define ISZ  96
#define OSZ  192
#define NX4  48            // output-x quads per row; lanes 0..47 active
#define YBC  8             // y-bricks per chunk (4 output rows each)
#define NYC  6             // y-chunks (6*8*4 = 192 output rows)
#define ZSTR (ISZ * ISZ)

typedef float vf4 __attribute__((ext_vector_type(4)));

struct Q4 { float a, b, c, d; };          // samples at xa, xm, xm+1, xd

__device__ __forceinline__ Q4 q_wsum(float wl, const Q4& L, float wh, const Q4& H) {
    Q4 q;
    q.a = fmaf(wl, L.a, wh * H.a);
    q.b = fmaf(wl, L.b, wh * H.b);
    q.c = fmaf(wl, L.c, wh * H.c);
    q.d = fmaf(wl, L.d, wh * H.d);
    return q;
}

__global__ __launch_bounds__(64)
void resize_flow_kernel(const float* __restrict__ in, float* __restrict__ out) {
    // chunked XCD swizzle (gridDim.x = 3456, divisible by 8)
    unsigned bid = blockIdx.x;
    unsigned wid = (bid & 7u) * (gridDim.x >> 3) + (bid >> 3);

    // wid -> (bc, k, yc); yc fastest so one XCD owns contiguous (bc,k) span
    int yc = (int)(wid % NYC);
    unsigned r = wid / NYC;
    int k  = (int)(r % ISZ);                // input z-plane; outputs 2k, 2k+1
    int bc = (int)(r / ISZ);                // 0..5

    int lane = (int)threadIdx.x;
    if (lane >= NX4) return;                // lanes 48..63 idle
    int x4 = lane;

    // input x indices for output quad [4*x4 .. 4*x4+3]
    int xm = 2 * x4;
    int xa = (x4 == 0)       ? ISZ - 1 : xm - 1;
    int xd = (x4 == NX4 - 1) ? 0       : xm + 2;

    // input planes (wrapped)
    int km = (k == 0)       ? ISZ - 1 : k - 1;
    int kp = (k == ISZ - 1) ? 0       : k + 1;

    const float* base = in + (size_t)bc * (ISZ * ZSTR);
    const float* Pm = base + (size_t)km * ZSTR;
    const float* P0 = base + (size_t)k  * ZSTR;
    const float* Pp = base + (size_t)kp * ZSTR;

    auto ld = [&](const float* row) -> Q4 {
        float2 m = *reinterpret_cast<const float2*>(row + xm);  // 8B aligned
        Q4 q; q.a = row[xa]; q.b = m.x; q.c = m.y; q.d = row[xd];
        return q;
    };
    // load 4 rows of one plane and y-blend into 4 output-y quads
    auto yblend = [&](const float* P, int ry0, int ry1, int ry2, int ry3, Q4* Y) {
        Q4 R0 = ld(P + ry0 * ISZ);
        Q4 R1 = ld(P + ry1 * ISZ);
        Q4 R2 = ld(P + ry2 * ISZ);
        Q4 R3 = ld(P + ry3 * ISZ);
        Y[0] = q_wsum(0.25f, R0, 0.75f, R1);
        Y[1] = q_wsum(0.75f, R1, 0.25f, R2);
        Y[2] = q_wsum(0.25f, R1, 0.75f, R2);
        Y[3] = q_wsum(0.75f, R2, 0.25f, R3);
    };

    // z weights with the ×2 rescale folded in:
    //   oz = 2k   : 0.5*P(k-1) + 1.5*P(k)
    //   oz = 2k+1 : 1.5*P(k)   + 0.5*P(k+1)
    float* out0 = out + (((size_t)bc * OSZ + 2 * k)     * OSZ) * OSZ + 4 * x4;
    float* out1 = out + (((size_t)bc * OSZ + 2 * k + 1) * OSZ) * OSZ + 4 * x4;

    auto store4 = [&](float wl, const Q4* YL, float wh, const Q4* YH,
                      float* pz, int oy) {
#pragma unroll
        for (int i = 0; i < 4; ++i) {
            Q4 q = q_wsum(wl, YL[i], wh, YH[i]);
            vf4 o;
            o.x = fmaf(0.25f, q.a, 0.75f * q.b);
            o.y = fmaf(0.75f, q.b, 0.25f * q.c);
            o.z = fmaf(0.25f, q.b, 0.75f * q.c);
            o.w = fmaf(0.75f, q.c, 0.25f * q.d);
            *reinterpret_cast<vf4*>(pz + (size_t)(oy + i) * OSZ) = o;
        }
    };

    Q4 Ym[4], Y0[4], Yp[4];
    for (int tyl = 0; tyl < YBC; ++tyl) {
        int ty = yc * YBC + tyl;            // global y-brick 0..47
        int jy = 2 * ty;
        int ry0 = (jy == 0) ? ISZ - 1 : jy - 1;
        int ry1 = jy, ry2 = jy + 1;
        int ry3 = (jy + 2 == ISZ) ? 0 : jy + 2;

        yblend(Pm, ry0, ry1, ry2, ry3, Ym);
        yblend(P0, ry0, ry1, ry2, ry3, Y0);
        yblend(Pp, ry0, ry1, ry2, ry3, Yp);

        store4(0.5f, Ym, 1.5f, Y0, out0, 4 * ty);   // oz = 2k
        store4(1.5f, Y0, 0.5f, Yp, out1, 4 * ty);   // oz = 2k+1
    }
}

extern "C" void kernel_launch(void* const* d_in, const int* in_sizes, int n_in,
                              void* d_out, int out_size, void* d_ws, size_t ws_size,
                              hipStream_t stream) {
    const float* in = (const float*)d_in[0];
    float* out = (float*)d_out;

    // 6 bc * 96 planes * 6 y-chunks = 3456 one-wave blocks (divisible by 8)
    int grid  = 6 * ISZ * NYC;
    int block = 64;

    resize_flow_kernel<<<grid, block, 0, stream>>>(in, out);
}

// Round 9
// 36.281 us; speedup vs baseline: 1.1454x; 1.1454x over previous
//
#include <hip/hip_runtime.h>

// ResizeFlow: factor-2 trilinear upsample, periodic (dft) wrap, edge anchor,
// then displacement rescale ×2 (folded into z-blend weights: 0.5/1.5).
// Input (2,3,96,96,96) f32 -> Output (2,3,192,192,192) f32.
//
// out[2k]   = 0.25*in[(k-1) mod 96] + 0.75*in[k]
// out[2k+1] = 0.75*in[k]            + 0.25*in[(k+1) mod 96]   (each axis)
//
// R9 single-variable change vs R5 (the 34.35 us best): INTRA-WAVE PHASE
// SEPARATION. All 4 input planes (48 loads) issue up front; all 16 float4
// stores issue back-to-back at the end. R5 interleaved load-plane / store-
// batch pairs; R8 showed fine-grained read<->write interleave is the worst
// case. This isolates read/write bus-turnaround clustering on the winning
// structure. Everything else identical to R5: 4z*4y*4x brick, block=64,
// 10368 blocks, chunked XCD swizzle, plain float4 stores.

#define ISZ  96
#define OSZ  192
#define NX4  48            // output-x quads per output row
#define NT   48            // bricks per axis (96 input / 2 per brick)
#define ZSTR (ISZ * ISZ)

typedef float vf4 __attribute__((ext_vector_type(4)));

struct Q4 { float a, b, c, d; };          // samples at xa, xm, xm+1, xd
struct PL { Q4 r0, r1, r2, r3; };         // one input plane's 4 rows

__device__ __forceinline__ Q4 q_wsum(float wl, const Q4& L, float wh, const Q4& H) {
    Q4 q;
    q.a = fmaf(wl, L.a, wh * H.a);
    q.b = fmaf(wl, L.b, wh * H.b);
    q.c = fmaf(wl, L.c, wh * H.c);
    q.d = fmaf(wl, L.d, wh * H.d);
    return q;
}
__device__ __forceinline__ Q4 q_scale(float w, const Q4& Y) {
    Q4 q; q.a = w * Y.a; q.b = w * Y.b; q.c = w * Y.c; q.d = w * Y.d; return q;
}
__device__ __forceinline__ void q_acc(Q4& O, float w, const Q4& Y) {
    O.a = fmaf(w, Y.a, O.a);
    O.b = fmaf(w, Y.b, O.b);
    O.c = fmaf(w, Y.c, O.c);
    O.d = fmaf(w, Y.d, O.d);
}

__global__ __launch_bounds__(64)
void resize_flow_kernel(const float* __restrict__ in, float* __restrict__ out) {
    // chunked XCD swizzle (gridDim.x = 10368, divisible by 8)
    unsigned bid = blockIdx.x;
    unsigned wid = (bid & 7u) * (gridDim.x >> 3) + (bid >> 3);
    unsigned t   = wid * 64u + threadIdx.x;

    int x4 = (int)(t % NX4);
    unsigned r = t / NX4;
    int ty = (int)(r % NT); r /= NT;
    int tz = (int)(r % NT);
    int bc = (int)(r / NT);                 // 0..5

    // input x indices for output quad [4*x4 .. 4*x4+3]
    int xm = 2 * x4;
    int xa = (x4 == 0)       ? ISZ - 1 : xm - 1;
    int xd = (x4 == NX4 - 1) ? 0       : xm + 2;

    // input rows / planes for this brick (wrapped)
    int ky  = 2 * ty;
    int ry0 = (ky == 0) ? ISZ - 1 : ky - 1;
    int ry1 = ky, ry2 = ky + 1;
    int ry3 = (ky + 2 == ISZ) ? 0 : ky + 2;

    int kz  = 2 * tz;
    int pz0 = (kz == 0) ? ISZ - 1 : kz - 1;
    int pz1 = kz, pz2 = kz + 1;
    int pz3 = (kz + 2 == ISZ) ? 0 : kz + 2;

    const float* base = in + (size_t)bc * (ISZ * ZSTR);

    auto ld = [&](const float* row) -> Q4 {
        float2 m = *reinterpret_cast<const float2*>(row + xm);  // 8B aligned
        Q4 q; q.a = row[xa]; q.b = m.x; q.c = m.y; q.d = row[xd];
        return q;
    };
    auto load_plane = [&](int p) -> PL {
        const float* pp = base + (size_t)p * ZSTR;
        PL L;
        L.r0 = ld(pp + ry0 * ISZ);
        L.r1 = ld(pp + ry1 * ISZ);
        L.r2 = ld(pp + ry2 * ISZ);
        L.r3 = ld(pp + ry3 * ISZ);
        return L;
    };
    auto yblend = [&](const PL& L, Q4* Y) {
        Y[0] = q_wsum(0.25f, L.r0, 0.75f, L.r1);   // oy = 4ty
        Y[1] = q_wsum(0.75f, L.r1, 0.25f, L.r2);   // oy+1
        Y[2] = q_wsum(0.25f, L.r1, 0.75f, L.r2);   // oy+2
        Y[3] = q_wsum(0.75f, L.r2, 0.25f, L.r3);   // oy+3
    };

    int oyb = 4 * ty, ozb = 4 * tz;
    auto xstore = [&](const Q4& q, int dz, int dy) {
        vf4 o;
        o.x = fmaf(0.25f, q.a, 0.75f * q.b);
        o.y = fmaf(0.75f, q.b, 0.25f * q.c);
        o.z = fmaf(0.25f, q.b, 0.75f * q.c);
        o.w = fmaf(0.75f, q.c, 0.25f * q.d);
        float* p = out + (((size_t)bc * OSZ + (ozb + dz)) * OSZ + (oyb + dy)) * OSZ + 4 * x4;
        *reinterpret_cast<vf4*>(p) = o;
    };

    // ---- READ PHASE: all 48 loads in flight before any compute/store ----
    PL L0 = load_plane(pz0);
    PL L1 = load_plane(pz1);
    PL L2 = load_plane(pz2);
    PL L3 = load_plane(pz3);

    // ---- COMPUTE PHASE: z weights (×2 rescale folded in: 0.5/1.5) ----
    //   oz = 4tz : 0.5*P(pz0) + 1.5*P(pz1)
    //   oz+1     : 1.5*P(pz1) + 0.5*P(pz2)
    //   oz+2     : 0.5*P(pz1) + 1.5*P(pz2)
    //   oz+3     : 1.5*P(pz2) + 0.5*P(pz3)
    Q4 Y[4];
    Q4 A[4], B[4], C[4], D[4];

    yblend(L0, Y);
#pragma unroll
    for (int i = 0; i < 4; ++i) A[i] = q_scale(0.5f, Y[i]);

    yblend(L1, Y);
#pragma unroll
    for (int i = 0; i < 4; ++i) {
        q_acc(A[i], 1.5f, Y[i]);
        B[i] = q_scale(1.5f, Y[i]);
        C[i] = q_scale(0.5f, Y[i]);
    }

    yblend(L2, Y);
#pragma unroll
    for (int i = 0; i < 4; ++i) {
        q_acc(B[i], 0.5f, Y[i]);
        q_acc(C[i], 1.5f, Y[i]);
        D[i] = q_scale(1.5f, Y[i]);
    }

    yblend(L3, Y);
#pragma unroll
    for (int i = 0; i < 4; ++i) q_acc(D[i], 0.5f, Y[i]);

    // ---- WRITE PHASE: all 16 stores back-to-back ----
#pragma unroll
    for (int i = 0; i < 4; ++i) xstore(A[i], 0, i);
#pragma unroll
    for (int i = 0; i < 4; ++i) xstore(B[i], 1, i);
#pragma unroll
    for (int i = 0; i < 4; ++i) xstore(C[i], 2, i);
#pragma unroll
    for (int i = 0; i < 4; ++i) xstore(D[i], 3, i);
}

extern "C" void kernel_launch(void* const* d_in, const int* in_sizes, int n_in,
                              void* d_out, int out_size, void* d_ws, size_t ws_size,
                              hipStream_t stream) {
    const float* in = (const float*)d_in[0];
    float* out = (float*)d_out;

    // 6 * 48 * 48 * 48 = 663,552 threads; 10,368 one-wave blocks (div by 8)
    int total = 6 * NT * NT * NX4;
    int block = 64;
    int grid  = total / block;

    resize_flow_kernel<<<grid, block, 0, stream>>>(in, out);
}